// Round 6
// baseline (987.917 us; speedup 1.0000x reference)
//
#include <hip/hip_runtime.h>
#include <math.h>

// ---------------------------------------------------------------------------
// AttnBlock: per-edge radial-MLP attention logits + segment softmax over dst.
//
// R6 structure (3 stream ops):
//   memset ssum[N]=0 (double)
//   K1 edge:  dot[e] -> d_out (fp32), atomicAdd ssum[v[e]] += exp_wide(dot)
//   K2 norm:  d_out[e] = (float)( exp_wide(dot) / ssum[v[e]] )
//
// KEY CHANGE vs R5: all 2016 radial-MLP weight floats are staged into LDS
// once per block; in-loop weight reads are broadcast ds_read_b64 into VGPRs.
// R3/R4/R5 all pinned at ~183 us / VALUBusy ~45% across EPT=1/2 and
// rolled/unrolled bodies -> stall is the SGPR-starved SMEM weight streaming
// (2030 floats through ~90 free SGPRs = ~20 s_waitcnt batches per wave).
// Also: the 27 scattered wj11 loads are hoisted to kernel entry so their
// VMEM latency hides under the 4-MLP compute instead of being exposed at
// the final epilogue.
//
// exp_wide: fp32 exp2 + bit-built 2^k scaling into double (R3-verified f64
// range semantics needed; fp32 exp overflowed in the tails).
// ---------------------------------------------------------------------------

#define TPB 256

typedef float f2 __attribute__((ext_vector_type(2)));
typedef int i2 __attribute__((ext_vector_type(2)));

static __device__ __forceinline__ f2 fma2(f2 a, f2 b, f2 c) {
    return __builtin_elementwise_fma(a, b, c);
}
static __device__ __forceinline__ f2 splat(float x) {
    f2 r;
    r.x = x;
    r.y = x;
    return r;
}
static __device__ __forceinline__ float get16(const f2* h, int c) {
    return (c & 1) ? h[c >> 1].y : h[c >> 1].x;
}

// exp(d) with f64-exp range semantics: result = 2^(d*log2e) as double.
static __device__ __forceinline__ double exp_wide(float d) {
    d = fminf(fmaxf(d, -1400.f), 1400.f);
    const float t = d * 1.44269504088896340736f;  // log2(e)
    const float k = rintf(t);
    const float p = exp2f(t - k);  // v_exp_f32, frac in [-0.5,0.5]
    const int ik = (int)k;         // |ik| <= 2020
    const int k1 = ik >> 1;
    const int k2 = ik - k1;        // k1+k2=ik, each in [-1010,1010]
    const double s1 = __hiloint2double((k1 + 1023) << 20, 0);  // 2^k1
    const double s2 = __hiloint2double((k2 + 1023) << 20, 0);  // 2^k2
    return ((double)p * s1) * s2;
}

// LayerNorm(16) + ReLU over h[8] (packed pairs). g/be point into LDS.
static __device__ __forceinline__ void ln_relu16(f2* h, const float* g,
                                                 const float* be) {
    const f2* g2 = (const f2*)g;
    const f2* be2 = (const f2*)be;
    f2 s = h[0] + h[1] + h[2] + h[3] + h[4] + h[5] + h[6] + h[7];
    const float mu = (s.x + s.y) * 0.0625f;
    const f2 mu2 = splat(mu);
    f2 vs = splat(0.f);
#pragma unroll
    for (int i = 0; i < 8; ++i) {
        f2 d = h[i] - mu2;
        vs = fma2(d, d, vs);
    }
    const float var = (vs.x + vs.y) * 0.0625f;
    const f2 r2 = splat(rsqrtf(var + 1e-5f));
    const f2 zero = splat(0.f);
#pragma unroll
    for (int i = 0; i < 8; ++i) {
        f2 t = (h[i] - mu2) * r2;
        h[i] = __builtin_elementwise_max(fma2(t, g2[i], be2[i]), zero);
    }
}

// LDS weight layout (floats):
//   rW1@0(192) rb1@192(64) g1@256(64) be1@320(64)
//   rW2@384(1024) rb2@1408(64) g2@1472(64) be2@1536(64)
//   [W3_00@1600(64) b3@1664(4)] [W3_01@1668 b3@1732] [W3_10@1736 b3@1800]
//   [W3_11@1804(192) b3_11@1996(12)] wq@2008(8)   -> total 2016
#define LDSW 2016

__global__ __launch_bounds__(TPB, 4) void edge_kernel(
    const float* __restrict__ f0, const float* __restrict__ f1,
    const float* __restrict__ dist, const int* __restrict__ u,
    const int* __restrict__ v, const float* __restrict__ wq,
    const float* __restrict__ wj00, const float* __restrict__ wj01,
    const float* __restrict__ wj10, const float* __restrict__ wj11,
    const float* __restrict__ rW1, const float* __restrict__ rb1,
    const float* __restrict__ g1, const float* __restrict__ be1,
    const float* __restrict__ rW2, const float* __restrict__ rb2,
    const float* __restrict__ g2, const float* __restrict__ be2,
    const float* __restrict__ W3_00, const float* __restrict__ b3_00,
    const float* __restrict__ W3_01, const float* __restrict__ b3_01,
    const float* __restrict__ W3_10, const float* __restrict__ b3_10,
    const float* __restrict__ W3_11, const float* __restrict__ b3_11,
    float* __restrict__ out, double* __restrict__ ssum, int E) {
    __shared__ float W[LDSW];
    {
        const int t = threadIdx.x;
        // each array staged cooperatively; sizes < TPB do one conditional copy
        for (int i = t; i < 192; i += TPB) W[0 + i] = rW1[i];
        if (t < 64) W[192 + t] = rb1[t];
        if (t < 64) W[256 + t] = g1[t];
        if (t < 64) W[320 + t] = be1[t];
        for (int i = t; i < 1024; i += TPB) W[384 + i] = rW2[i];
        if (t < 64) W[1408 + t] = rb2[t];
        if (t < 64) W[1472 + t] = g2[t];
        if (t < 64) W[1536 + t] = be2[t];
        if (t < 64) W[1600 + t] = W3_00[t];
        if (t < 4) W[1664 + t] = b3_00[t];
        if (t < 64) W[1668 + t] = W3_01[t];
        if (t < 4) W[1732 + t] = b3_01[t];
        if (t < 64) W[1736 + t] = W3_10[t];
        if (t < 4) W[1800 + t] = b3_10[t];
        for (int i = t; i < 192; i += TPB) W[1804 + i] = W3_11[i];
        if (t < 12) W[1996 + t] = b3_11[t];
        if (t < 8) W[2008 + t] = wq[t];
    }
    __syncthreads();

    const int e = blockIdx.x * blockDim.x + threadIdx.x;
    if (e >= E) return;

    // ---- all per-edge global loads issued up front ----
    const int uu = __builtin_nontemporal_load(u + e);
    const int vv = v[e];
    const float dd = __builtin_nontemporal_load(dist + e);
    const float w00 = __builtin_nontemporal_load(wj00 + e);
    float w01[3], w10[3], w11[27];
    {
        const float* p01 = wj01 + (size_t)e * 3;
        const float* p10 = wj10 + (size_t)e * 3;
        const float* p11 = wj11 + (size_t)e * 27;
#pragma unroll
        for (int c = 0; c < 3; ++c) w01[c] = __builtin_nontemporal_load(p01 + c);
#pragma unroll
        for (int c = 0; c < 3; ++c) w10[c] = __builtin_nontemporal_load(p10 + c);
#pragma unroll
        for (int c = 0; c < 27; ++c)
            w11[c] = __builtin_nontemporal_load(p11 + c);
    }

    const float f0u0 = f0[uu * 2 + 0];
    const float f0u1 = f0[uu * 2 + 1];
    const float f0v0 = f0[vv * 2 + 0];
    const float f0v1 = f0[vv * 2 + 1];
    float f1v[2][3];
#pragma unroll
    for (int i = 0; i < 2; ++i)
#pragma unroll
        for (int m = 0; m < 3; ++m) f1v[i][m] = f1[vv * 6 + i * 3 + m];

    const float vec0 = f0u0 * f0v0;
    const float vec1 = f0u1 * f0v1;
    const float vec2 = dd;

    float acc0[2] = {0.f, 0.f};
    float acc1[2][3] = {{0.f, 0.f, 0.f}, {0.f, 0.f, 0.f}};

    // ---- rolled loop over the 4 radial MLPs (wave-uniform control flow) ----
#pragma clang loop unroll(disable)
    for (int i = 0; i < 4; ++i) {
        const float* W1 = W + i * 48;
        const float* b1 = W + 192 + i * 16;
        const float* g1i = W + 256 + i * 16;
        const float* be1i = W + 320 + i * 16;
        const float* W2 = W + 384 + i * 256;
        const float* b2 = W + 1408 + i * 16;
        const float* g2i = W + 1472 + i * 16;
        const float* be2i = W + 1536 + i * 16;

        // layer1: 3 -> 16
        f2 h[8];
        {
            const f2* W1r0 = (const f2*)W1;
            const f2* W1r1 = (const f2*)(W1 + 16);
            const f2* W1r2 = (const f2*)(W1 + 32);
            const f2* b1v = (const f2*)b1;
            const f2 a = splat(vec0), b = splat(vec1), c = splat(vec2);
#pragma unroll
            for (int j = 0; j < 8; ++j)
                h[j] = fma2(a, W1r0[j],
                            fma2(b, W1r1[j], fma2(c, W1r2[j], b1v[j])));
        }
        ln_relu16(h, g1i, be1i);

        // layer2: 16 -> 16
        f2 h2[8];
        {
            const f2* b2v = (const f2*)b2;
#pragma unroll
            for (int j = 0; j < 8; ++j) h2[j] = b2v[j];
#pragma unroll
            for (int c = 0; c < 16; ++c) {
                const f2 hc = splat(get16(h, c));
                const f2* row = (const f2*)(W2 + c * 16);
#pragma unroll
                for (int j = 0; j < 8; ++j) h2[j] = fma2(hc, row[j], h2[j]);
            }
        }
        ln_relu16(h2, g2i, be2i);

        // layer3 + epilogue (wave-uniform branches on i)
        if (i == 3) {
            const float* W3p = W + 1804;
            const float* b3p = W + 1996;
#pragma unroll
            for (int j = 0; j < 3; ++j) {
                f2 p0 = *(const f2*)(b3p + j * 4);
                f2 p1 = *(const f2*)(b3p + j * 4 + 2);
#pragma unroll
                for (int c = 0; c < 16; ++c) {
                    const f2 hc = splat(get16(h2, c));
                    p0 = fma2(hc, *(const f2*)(W3p + c * 12 + j * 4), p0);
                    p1 = fma2(hc, *(const f2*)(W3p + c * 12 + j * 4 + 2), p1);
                }
#pragma unroll
                for (int m = 0; m < 3; ++m) {
                    const float a0 = w11[j * 9 + m * 3 + 0];
                    const float a1 = w11[j * 9 + m * 3 + 1];
                    const float a2 = w11[j * 9 + m * 3 + 2];
                    const float B0 =
                        a0 * f1v[0][0] + a1 * f1v[0][1] + a2 * f1v[0][2];
                    const float B1 =
                        a0 * f1v[1][0] + a1 * f1v[1][1] + a2 * f1v[1][2];
                    acc1[0][m] += p0.x * B0 + p0.y * B1;
                    acc1[1][m] += p1.x * B0 + p1.y * B1;
                }
            }
        } else {
            const float* W3p = W + 1600 + i * 68;
            const float* b3p = W3p + 64;
            f2 p0 = *(const f2*)(b3p);
            f2 p1 = *(const f2*)(b3p + 2);
#pragma unroll
            for (int c = 0; c < 16; ++c) {
                const f2 hc = splat(get16(h2, c));
                p0 = fma2(hc, *(const f2*)(W3p + c * 4), p0);
                p1 = fma2(hc, *(const f2*)(W3p + c * 4 + 2), p1);
            }
            if (i == 0) {
                acc0[0] += w00 * (p0.x * f0v0 + p0.y * f0v1);
                acc0[1] += w00 * (p1.x * f0v0 + p1.y * f0v1);
            } else if (i == 1) {
                const float s0 =
                    w01[0] * f1v[0][0] + w01[1] * f1v[0][1] + w01[2] * f1v[0][2];
                const float s1 =
                    w01[0] * f1v[1][0] + w01[1] * f1v[1][1] + w01[2] * f1v[1][2];
                acc0[0] += p0.x * s0 + p0.y * s1;
                acc0[1] += p1.x * s0 + p1.y * s1;
            } else {
                const float t0 = p0.x * f0v0 + p0.y * f0v1;
                const float t1 = p1.x * f0v0 + p1.y * f0v1;
#pragma unroll
                for (int m = 0; m < 3; ++m) {
                    acc1[0][m] += w10[m] * t0;
                    acc1[1][m] += w10[m] * t1;
                }
            }
        }
    }

    // ---- q[v] . k_feat ----  wq[d][o][i] = wq[d*4+o*2+i]
    float dot = 0.f;
    {
        const float* wqs = W + 2008;
        const float q00 = wqs[0] * f0v0 + wqs[1] * f0v1;
        const float q01 = wqs[2] * f0v0 + wqs[3] * f0v1;
        dot += q00 * acc0[0] + q01 * acc0[1];
#pragma unroll
        for (int m = 0; m < 3; ++m) {
            const float q1m0 = wqs[4] * f1v[0][m] + wqs[5] * f1v[1][m];
            const float q1m1 = wqs[6] * f1v[0][m] + wqs[7] * f1v[1][m];
            dot += q1m0 * acc1[0][m] + q1m1 * acc1[1][m];
        }
    }

    __builtin_nontemporal_store(dot, out + e);
    atomicAdd(&ssum[vv], exp_wide(dot));
}

__global__ void norm_kernel(float* __restrict__ out, const int* __restrict__ v,
                            const double* __restrict__ ssum, int E) {
    const int t = blockIdx.x * blockDim.x + threadIdx.x;
    const int e0 = t * 2;
    if (e0 >= E) return;
    if (e0 + 1 < E) {
        const f2 dv = *((const f2*)out + t);
        const i2 vv = *((const i2*)v + t);
        const double s0 = ssum[vv.x];
        const double s1 = ssum[vv.y];
        f2 r;
        r.x = (float)(exp_wide(dv.x) / s0);
        r.y = (float)(exp_wide(dv.y) / s1);
        __builtin_nontemporal_store(r, (f2*)out + t);
    } else {
        out[e0] = (float)(exp_wide(out[e0]) / ssum[v[e0]]);
    }
}

extern "C" void kernel_launch(void* const* d_in, const int* in_sizes, int n_in,
                              void* d_out, int out_size, void* d_ws,
                              size_t ws_size, hipStream_t stream) {
    const float* f0 = (const float*)d_in[0];
    const float* f1 = (const float*)d_in[1];
    const float* dist = (const float*)d_in[2];
    const int* u = (const int*)d_in[3];
    const int* v = (const int*)d_in[4];
    const float* wq = (const float*)d_in[5];
    const float* wj00 = (const float*)d_in[6];
    const float* wj01 = (const float*)d_in[7];
    const float* wj10 = (const float*)d_in[8];
    const float* wj11 = (const float*)d_in[9];
    const float* rW1 = (const float*)d_in[10];
    const float* rb1 = (const float*)d_in[11];
    const float* g1 = (const float*)d_in[12];
    const float* be1 = (const float*)d_in[13];
    const float* rW2 = (const float*)d_in[14];
    const float* rb2 = (const float*)d_in[15];
    const float* g2 = (const float*)d_in[16];
    const float* be2 = (const float*)d_in[17];
    const float* W3_00 = (const float*)d_in[18];
    const float* b3_00 = (const float*)d_in[19];
    const float* W3_01 = (const float*)d_in[20];
    const float* b3_01 = (const float*)d_in[21];
    const float* W3_10 = (const float*)d_in[22];
    const float* b3_10 = (const float*)d_in[23];
    const float* W3_11 = (const float*)d_in[24];
    const float* b3_11 = (const float*)d_in[25];

    const int N = in_sizes[0] / 2;  // f0 is [N,2,1]
    const int E = in_sizes[2];      // dist is [E]

    double* ssum = (double*)d_ws;
    float* out = (float*)d_out;

    const int ge = (E + TPB - 1) / TPB;
    const int gp = ((E + 1) / 2 + TPB - 1) / TPB;

    hipMemsetAsync(ssum, 0, (size_t)N * sizeof(double), stream);
    edge_kernel<<<ge, TPB, 0, stream>>>(
        f0, f1, dist, u, v, wq, wj00, wj01, wj10, wj11, rW1, rb1, g1, be1, rW2,
        rb2, g2, be2, W3_00, b3_00, W3_01, b3_01, W3_10, b3_10, W3_11, b3_11,
        out, ssum, E);
    norm_kernel<<<gp, TPB, 0, stream>>>(out, v, ssum, E);
}

// Round 7
// 431.897 us; speedup vs baseline: 2.2874x; 2.2874x over previous
//
#include <hip/hip_runtime.h>
#include <math.h>

// ---------------------------------------------------------------------------
// AttnBlock: per-edge radial-MLP attention logits + segment softmax over dst.
//
// R7 structure (3 stream ops):
//   memset ssum[N]=0 (double)
//   K1 edge:  dot[e] -> d_out (fp32), atomicAdd ssum[v[e]] += exp_wide(dot)
//   K2 norm:  d_out[e] = (float)( exp_wide(dot) / ssum[v[e]] )
//
// KEY CHANGE vs R5: EDGE-PAIR PACKING. Each thread computes 2 edges with all
// per-channel state as f2 {edge0,edge1}; every fma/LN/epilogue op is one
// packed v_pk_fma_f32-class instruction for both edges, weights as SGPR
// broadcast (<=1 sgpr per VALU inst). R3/R4/R5 invariance (183us across
// EPT1/2, rolled/unrolled, SMEM traffic halved) shows total VALU issue is
// the binding resource -> halve it wholesale.
// R6 lesson: do NOT hoist wj arrays (33 live floats -> scratch spill, 2.6GB
// of HBM traffic); keep wj loads in-branch like R5.
//
// exp_wide: fp32 exp2 + bit-built 2^k scaling into double (R3-verified f64
// range semantics needed; fp32 exp overflowed in the tails).
// ---------------------------------------------------------------------------

#define TPB 256

typedef float f2 __attribute__((ext_vector_type(2)));
typedef int i2 __attribute__((ext_vector_type(2)));

static __device__ __forceinline__ f2 fma2(f2 a, f2 b, f2 c) {
    return __builtin_elementwise_fma(a, b, c);
}
static __device__ __forceinline__ f2 splat(float x) {
    f2 r;
    r.x = x;
    r.y = x;
    return r;
}
static __device__ __forceinline__ f2 mk2(float a, float b) {
    f2 r;
    r.x = a;
    r.y = b;
    return r;
}

// exp(d) with f64-exp range semantics: result = 2^(d*log2e) as double.
static __device__ __forceinline__ double exp_wide(float d) {
    d = fminf(fmaxf(d, -1400.f), 1400.f);
    const float t = d * 1.44269504088896340736f;  // log2(e)
    const float k = rintf(t);
    const float p = exp2f(t - k);  // v_exp_f32, frac in [-0.5,0.5]
    const int ik = (int)k;         // |ik| <= 2020
    const int k1 = ik >> 1;
    const int k2 = ik - k1;        // k1+k2=ik, each in [-1010,1010]
    const double s1 = __hiloint2double((k1 + 1023) << 20, 0);  // 2^k1
    const double s2 = __hiloint2double((k2 + 1023) << 20, 0);  // 2^k2
    return ((double)p * s1) * s2;
}

// LayerNorm(16)+ReLU over h[16], each f2 = {edge0,edge1}. g/be scalar (SGPR).
static __device__ __forceinline__ void ln_relu16p(f2* h, const float* __restrict__ g,
                                                  const float* __restrict__ be) {
    f2 s = splat(0.f);
#pragma unroll
    for (int j = 0; j < 16; ++j) s = s + h[j];
    const f2 mu = s * splat(0.0625f);
    f2 vs = splat(0.f);
#pragma unroll
    for (int j = 0; j < 16; ++j) {
        h[j] = h[j] - mu;  // keep centered value
        vs = fma2(h[j], h[j], vs);
    }
    const f2 var = vs * splat(0.0625f);
    const f2 r = mk2(rsqrtf(var.x + 1e-5f), rsqrtf(var.y + 1e-5f));
    const f2 zero = splat(0.f);
#pragma unroll
    for (int j = 0; j < 16; ++j) {
        const f2 t = h[j] * r;
        h[j] = __builtin_elementwise_max(fma2(t, splat(g[j]), splat(be[j])),
                                         zero);
    }
}

__global__ __launch_bounds__(TPB, 3) void edge_kernel(
    const float* __restrict__ f0, const float* __restrict__ f1,
    const float* __restrict__ dist, const int* __restrict__ u,
    const int* __restrict__ v, const float* __restrict__ wq,
    const float* __restrict__ wj00, const float* __restrict__ wj01,
    const float* __restrict__ wj10, const float* __restrict__ wj11,
    const float* __restrict__ rW1, const float* __restrict__ rb1,
    const float* __restrict__ g1, const float* __restrict__ be1,
    const float* __restrict__ rW2, const float* __restrict__ rb2,
    const float* __restrict__ g2, const float* __restrict__ be2,
    const float* __restrict__ W3_00, const float* __restrict__ b3_00,
    const float* __restrict__ W3_01, const float* __restrict__ b3_01,
    const float* __restrict__ W3_10, const float* __restrict__ b3_10,
    const float* __restrict__ W3_11, const float* __restrict__ b3_11,
    float* __restrict__ out, double* __restrict__ ssum, int E) {
    const int t = blockIdx.x * blockDim.x + threadIdx.x;
    const int e0 = t * 2;
    if (e0 >= E) return;
    const bool has1 = (e0 + 1) < E;
    const int e1 = has1 ? e0 + 1 : e0;

    // ---- per-pair streams ----
    int u0, u1, v0, v1;
    f2 dd, w00;
    if (has1) {
        const i2 uu2 = *((const i2*)u + t);
        const i2 vv2 = *((const i2*)v + t);
        u0 = uu2.x;
        u1 = uu2.y;
        v0 = vv2.x;
        v1 = vv2.y;
        dd = *((const f2*)dist + t);
        w00 = *((const f2*)wj00 + t);
    } else {
        u0 = u1 = u[e0];
        v0 = v1 = v[e0];
        dd = splat(dist[e0]);
        w00 = splat(wj00[e0]);
    }

    // gathers; per-edge contiguous pairs then repacked into {e0,e1} lanes
    const f2 a0 = *(const f2*)(f0 + (size_t)u0 * 2);  // edge0: ch0,ch1
    const f2 a1 = *(const f2*)(f0 + (size_t)u1 * 2);
    const f2 b0 = *(const f2*)(f0 + (size_t)v0 * 2);
    const f2 b1v_ = *(const f2*)(f0 + (size_t)v1 * 2);
    const f2 fu0 = mk2(a0.x, a1.x);  // ch0 of u, both edges
    const f2 fu1 = mk2(a0.y, a1.y);
    const f2 fv0 = mk2(b0.x, b1v_.x);
    const f2 fv1 = mk2(b0.y, b1v_.y);

    f2 f1v[2][3];  // f1[v][i][m], packed over edges
    {
        const float* p0 = f1 + (size_t)v0 * 6;
        const float* p1 = f1 + (size_t)v1 * 6;
#pragma unroll
        for (int i = 0; i < 2; ++i)
#pragma unroll
            for (int m = 0; m < 3; ++m)
                f1v[i][m] = mk2(p0[i * 3 + m], p1[i * 3 + m]);
    }

    const f2 vec0 = fu0 * fv0;
    const f2 vec1 = fu1 * fv1;
    const f2 vec2 = dd;

    f2 acc0[2] = {splat(0.f), splat(0.f)};
    f2 acc1[2][3];
#pragma unroll
    for (int o = 0; o < 2; ++o)
#pragma unroll
        for (int m = 0; m < 3; ++m) acc1[o][m] = splat(0.f);

    // ---- rolled loop over the 4 radial MLPs (wave-uniform control flow) ----
#pragma clang loop unroll(disable)
    for (int i = 0; i < 4; ++i) {
        const float* W1 = rW1 + i * 48;
        const float* b1 = rb1 + i * 16;
        const float* g1i = g1 + i * 16;
        const float* be1i = be1 + i * 16;
        const float* W2 = rW2 + i * 256;
        const float* b2 = rb2 + i * 16;
        const float* g2i = g2 + i * 16;
        const float* be2i = be2 + i * 16;

        // layer1: 3 -> 16 (weights scalar-broadcast, state f2 over edges)
        f2 h[16];
#pragma unroll
        for (int j = 0; j < 16; ++j)
            h[j] = fma2(vec0, splat(W1[j]),
                        fma2(vec1, splat(W1[16 + j]),
                             fma2(vec2, splat(W1[32 + j]), splat(b1[j]))));
        ln_relu16p(h, g1i, be1i);

        // layer2: 16 -> 16
        f2 h2[16];
#pragma unroll
        for (int j = 0; j < 16; ++j) h2[j] = splat(b2[j]);
#pragma unroll
        for (int c = 0; c < 16; ++c) {
#pragma unroll
            for (int j = 0; j < 16; ++j)
                h2[j] = fma2(h[c], splat(W2[c * 16 + j]), h2[j]);
        }
        ln_relu16p(h2, g2i, be2i);

        // layer3 + epilogue (wave-uniform branches on i)
        if (i == 3) {
#pragma unroll
            for (int j = 0; j < 3; ++j) {
                f2 p00 = splat(b3_11[j * 4 + 0]);
                f2 p01 = splat(b3_11[j * 4 + 1]);
                f2 p10 = splat(b3_11[j * 4 + 2]);
                f2 p11 = splat(b3_11[j * 4 + 3]);
#pragma unroll
                for (int c = 0; c < 16; ++c) {
                    const f2 hc = h2[c];
                    p00 = fma2(hc, splat(W3_11[c * 12 + j * 4 + 0]), p00);
                    p01 = fma2(hc, splat(W3_11[c * 12 + j * 4 + 1]), p01);
                    p10 = fma2(hc, splat(W3_11[c * 12 + j * 4 + 2]), p10);
                    p11 = fma2(hc, splat(W3_11[c * 12 + j * 4 + 3]), p11);
                }
#pragma unroll
                for (int m = 0; m < 3; ++m) {
                    const f2 c0 = mk2(wj11[(size_t)e0 * 27 + j * 9 + m * 3 + 0],
                                      wj11[(size_t)e1 * 27 + j * 9 + m * 3 + 0]);
                    const f2 c1 = mk2(wj11[(size_t)e0 * 27 + j * 9 + m * 3 + 1],
                                      wj11[(size_t)e1 * 27 + j * 9 + m * 3 + 1]);
                    const f2 c2 = mk2(wj11[(size_t)e0 * 27 + j * 9 + m * 3 + 2],
                                      wj11[(size_t)e1 * 27 + j * 9 + m * 3 + 2]);
                    const f2 B0 = c0 * f1v[0][0] + c1 * f1v[0][1] + c2 * f1v[0][2];
                    const f2 B1 = c0 * f1v[1][0] + c1 * f1v[1][1] + c2 * f1v[1][2];
                    acc1[0][m] = fma2(p00, B0, fma2(p01, B1, acc1[0][m]));
                    acc1[1][m] = fma2(p10, B0, fma2(p11, B1, acc1[1][m]));
                }
            }
        } else {
            const float* W3p;
            const float* b3p;
            if (i == 0) {
                W3p = W3_00;
                b3p = b3_00;
            } else if (i == 1) {
                W3p = W3_01;
                b3p = b3_01;
            } else {
                W3p = W3_10;
                b3p = b3_10;
            }
            f2 p00 = splat(b3p[0]);
            f2 p01 = splat(b3p[1]);
            f2 p10 = splat(b3p[2]);
            f2 p11 = splat(b3p[3]);
#pragma unroll
            for (int c = 0; c < 16; ++c) {
                const f2 hc = h2[c];
                p00 = fma2(hc, splat(W3p[c * 4 + 0]), p00);
                p01 = fma2(hc, splat(W3p[c * 4 + 1]), p01);
                p10 = fma2(hc, splat(W3p[c * 4 + 2]), p10);
                p11 = fma2(hc, splat(W3p[c * 4 + 3]), p11);
            }
            if (i == 0) {
                acc0[0] = fma2(w00, fma2(p00, fv0, p01 * fv1), acc0[0]);
                acc0[1] = fma2(w00, fma2(p10, fv0, p11 * fv1), acc0[1]);
            } else if (i == 1) {
                f2 c0 = mk2(wj01[(size_t)e0 * 3 + 0], wj01[(size_t)e1 * 3 + 0]);
                f2 c1 = mk2(wj01[(size_t)e0 * 3 + 1], wj01[(size_t)e1 * 3 + 1]);
                f2 c2 = mk2(wj01[(size_t)e0 * 3 + 2], wj01[(size_t)e1 * 3 + 2]);
                const f2 s0 = c0 * f1v[0][0] + c1 * f1v[0][1] + c2 * f1v[0][2];
                const f2 s1 = c0 * f1v[1][0] + c1 * f1v[1][1] + c2 * f1v[1][2];
                acc0[0] = fma2(p00, s0, fma2(p01, s1, acc0[0]));
                acc0[1] = fma2(p10, s0, fma2(p11, s1, acc0[1]));
            } else {
                const f2 t0 = fma2(p00, fv0, p01 * fv1);
                const f2 t1 = fma2(p10, fv0, p11 * fv1);
#pragma unroll
                for (int m = 0; m < 3; ++m) {
                    const f2 wm =
                        mk2(wj10[(size_t)e0 * 3 + m], wj10[(size_t)e1 * 3 + m]);
                    acc1[0][m] = fma2(wm, t0, acc1[0][m]);
                    acc1[1][m] = fma2(wm, t1, acc1[1][m]);
                }
            }
        }
    }

    // ---- q[v] . k_feat ----  wq[d][o][i] = wq[d*4+o*2+i]
    f2 dot = splat(0.f);
    {
        const f2 q00 = fma2(splat(wq[0]), fv0, splat(wq[1]) * fv1);
        const f2 q01 = fma2(splat(wq[2]), fv0, splat(wq[3]) * fv1);
        dot = fma2(q00, acc0[0], fma2(q01, acc0[1], dot));
#pragma unroll
        for (int m = 0; m < 3; ++m) {
            const f2 q1m0 =
                fma2(splat(wq[4]), f1v[0][m], splat(wq[5]) * f1v[1][m]);
            const f2 q1m1 =
                fma2(splat(wq[6]), f1v[0][m], splat(wq[7]) * f1v[1][m]);
            dot = fma2(q1m0, acc1[0][m], fma2(q1m1, acc1[1][m], dot));
        }
    }

    if (has1) {
        __builtin_nontemporal_store(dot, (f2*)out + t);
        atomicAdd(&ssum[v0], exp_wide(dot.x));
        atomicAdd(&ssum[v1], exp_wide(dot.y));
    } else {
        out[e0] = dot.x;
        atomicAdd(&ssum[v0], exp_wide(dot.x));
    }
}

__global__ void norm_kernel(float* __restrict__ out, const int* __restrict__ v,
                            const double* __restrict__ ssum, int E) {
    const int t = blockIdx.x * blockDim.x + threadIdx.x;
    const int e0 = t * 2;
    if (e0 >= E) return;
    if (e0 + 1 < E) {
        const f2 dv = *((const f2*)out + t);
        const i2 vv = *((const i2*)v + t);
        const double s0 = ssum[vv.x];
        const double s1 = ssum[vv.y];
        f2 r;
        r.x = (float)(exp_wide(dv.x) / s0);
        r.y = (float)(exp_wide(dv.y) / s1);
        __builtin_nontemporal_store(r, (f2*)out + t);
    } else {
        out[e0] = (float)(exp_wide(out[e0]) / ssum[v[e0]]);
    }
}

extern "C" void kernel_launch(void* const* d_in, const int* in_sizes, int n_in,
                              void* d_out, int out_size, void* d_ws,
                              size_t ws_size, hipStream_t stream) {
    const float* f0 = (const float*)d_in[0];
    const float* f1 = (const float*)d_in[1];
    const float* dist = (const float*)d_in[2];
    const int* u = (const int*)d_in[3];
    const int* v = (const int*)d_in[4];
    const float* wq = (const float*)d_in[5];
    const float* wj00 = (const float*)d_in[6];
    const float* wj01 = (const float*)d_in[7];
    const float* wj10 = (const float*)d_in[8];
    const float* wj11 = (const float*)d_in[9];
    const float* rW1 = (const float*)d_in[10];
    const float* rb1 = (const float*)d_in[11];
    const float* g1 = (const float*)d_in[12];
    const float* be1 = (const float*)d_in[13];
    const float* rW2 = (const float*)d_in[14];
    const float* rb2 = (const float*)d_in[15];
    const float* g2 = (const float*)d_in[16];
    const float* be2 = (const float*)d_in[17];
    const float* W3_00 = (const float*)d_in[18];
    const float* b3_00 = (const float*)d_in[19];
    const float* W3_01 = (const float*)d_in[20];
    const float* b3_01 = (const float*)d_in[21];
    const float* W3_10 = (const float*)d_in[22];
    const float* b3_10 = (const float*)d_in[23];
    const float* W3_11 = (const float*)d_in[24];
    const float* b3_11 = (const float*)d_in[25];

    const int N = in_sizes[0] / 2;  // f0 is [N,2,1]
    const int E = in_sizes[2];      // dist is [E]

    double* ssum = (double*)d_ws;
    float* out = (float*)d_out;

    const int gp = ((E + 1) / 2 + TPB - 1) / TPB;

    hipMemsetAsync(ssum, 0, (size_t)N * sizeof(double), stream);
    edge_kernel<<<gp, TPB, 0, stream>>>(
        f0, f1, dist, u, v, wq, wj00, wj01, wj10, wj11, rW1, rb1, g1, be1, rW2,
        rb2, g2, be2, W3_00, b3_00, W3_01, b3_01, W3_10, b3_10, W3_11, b3_11,
        out, ssum, E);
    norm_kernel<<<gp, TPB, 0, stream>>>(out, v, ssum, E);
}